// Round 1
// baseline (1302.559 us; speedup 1.0000x reference)
//
#include <hip/hip_runtime.h>

// Problem constants
#define LCc 1024
#define LQq 512
#define BB  64
#define DDim 256

typedef __attribute__((ext_vector_type(8))) short bf16x8;
typedef __attribute__((ext_vector_type(4))) float f32x4;
typedef __attribute__((ext_vector_type(4))) unsigned short us4;
typedef __attribute__((ext_vector_type(8))) unsigned short us8;

static __device__ __forceinline__ unsigned short f2b(float f) {
  unsigned u = __builtin_bit_cast(unsigned, f);
  unsigned r = u + 0x7FFFu + ((u >> 16) & 1u);   // RNE to bf16
  return (unsigned short)(r >> 16);
}

static __device__ __forceinline__ bf16x8 ldb8(const unsigned short* p) {
  return *(const bf16x8*)p;
}

static __device__ __forceinline__ f32x4 MFMA16(bf16x8 a, bf16x8 b, f32x4 c) {
  return __builtin_amdgcn_mfma_f32_16x16x32_bf16(a, b, c, 0, 0, 0);
}

// ---------------------------------------------------------------------------
// prep_C: Cw[b][c][d] = bf16(C*w4mlu); rowAdd[b][c] = dot(C_row, w4C)  (fp32)
// grid: B*LC blocks of 256 (one block per (b,c) row)
// ---------------------------------------------------------------------------
__global__ __launch_bounds__(256) void prep_C(const float* __restrict__ C,
    const float* __restrict__ w4C, const float* __restrict__ w4mlu,
    unsigned short* __restrict__ Cw, float* __restrict__ rowAdd) {
  int blk = blockIdx.x;
  int c = blk & (LCc - 1), b = blk >> 10;
  int t = threadIdx.x;
  float v = C[((size_t)c * BB + b) * DDim + t];
  Cw[(((size_t)b << 10) + c) * DDim + t] = f2b(v * w4mlu[t]);
  float s = v * w4C[t];
  #pragma unroll
  for (int off = 1; off < 64; off <<= 1) s += __shfl_xor(s, off);
  __shared__ float red[4];
  if ((t & 63) == 0) red[t >> 6] = s;
  __syncthreads();
  if (t == 0) rowAdd[((size_t)b << 10) + c] = red[0] + red[1] + red[2] + red[3];
}

// ---------------------------------------------------------------------------
// prep_Q: Qb[b][q][d] = bf16(Q); colAdd[b][q] = dot(Q_row, w4Q) + bias; colL=0
// ---------------------------------------------------------------------------
__global__ __launch_bounds__(256) void prep_Q(const float* __restrict__ Q,
    const float* __restrict__ w4Q, const float* __restrict__ bias,
    unsigned short* __restrict__ Qb, float* __restrict__ colAdd,
    float* __restrict__ colL) {
  int blk = blockIdx.x;
  int q = blk & (LQq - 1), b = blk >> 9;
  int t = threadIdx.x;
  float v = Q[((size_t)q * BB + b) * DDim + t];
  Qb[(((size_t)b << 9) + q) * DDim + t] = f2b(v);
  float s = v * w4Q[t];
  #pragma unroll
  for (int off = 1; off < 64; off <<= 1) s += __shfl_xor(s, off);
  __shared__ float red[4];
  if ((t & 63) == 0) red[t >> 6] = s;
  __syncthreads();
  if (t == 0) {
    colAdd[((size_t)b << 9) + q] = red[0] + red[1] + red[2] + red[3] + bias[0];
    colL[((size_t)b << 9) + q] = 0.0f;   // init for k_stats atomics
  }
}

// ---------------------------------------------------------------------------
// transpose_b16: X (L,B,D) fp32 seq-major -> XT (B,D,L) bf16
// grid (L/64, D/64, B), 256 threads, LDS 64x65 tile
// ---------------------------------------------------------------------------
__global__ __launch_bounds__(256) void transpose_b16(const float* __restrict__ X,
    unsigned short* __restrict__ XT, int L) {
  __shared__ unsigned short tile[64][65];
  int l0 = blockIdx.x * 64, d0 = blockIdx.y * 64, b = blockIdx.z;
  int t = threadIdx.x, r = t >> 2, g = t & 3;
  const float* src = X + ((size_t)(l0 + r) * BB + b) * DDim + d0 + g * 16;
  #pragma unroll
  for (int i = 0; i < 4; i++) {
    float4 v = ((const float4*)src)[i];
    tile[r][g * 16 + i * 4 + 0] = f2b(v.x);
    tile[r][g * 16 + i * 4 + 1] = f2b(v.y);
    tile[r][g * 16 + i * 4 + 2] = f2b(v.z);
    tile[r][g * 16 + i * 4 + 3] = f2b(v.w);
  }
  __syncthreads();
  unsigned short* dst = XT + ((size_t)b * DDim + d0 + r) * L + l0 + g * 16;
  us8 o0, o1;
  #pragma unroll
  for (int j = 0; j < 8; j++) {
    o0[j] = tile[g * 16 + j][r];
    o1[j] = tile[g * 16 + 8 + j][r];
  }
  *(us8*)dst = o0;
  *(us8*)(dst + 8) = o1;
}

// ---------------------------------------------------------------------------
// k_stats: rowL[b][c] = sum_q exp(S), colL[b][q] = sum_c exp(S)
// grid: B*16 blocks (b, c-tile of 64), 4 waves; wave w -> c-band of 16
// ---------------------------------------------------------------------------
__global__ __launch_bounds__(256, 2) void k_stats(const unsigned short* __restrict__ Cw,
    const unsigned short* __restrict__ Qb, const float* __restrict__ rowAdd,
    const float* __restrict__ colAdd, float* __restrict__ rowL,
    float* __restrict__ colL) {
  int blk = blockIdx.x;
  int b = blk >> 4, ct = blk & 15;
  int t = threadIdx.x, w = t >> 6, lane = t & 63;
  int col = lane & 15, quad = lane >> 4;
  int c0 = ct * 64 + w * 16;
  __shared__ float colAcc[LQq];
  for (int i = t; i < LQq; i += 256) colAcc[i] = 0.f;
  __syncthreads();

  const unsigned short* aPtr = Cw + (((size_t)b << 10) + c0 + col) * DDim + quad * 8;
  bf16x8 afrag[8];
  #pragma unroll
  for (int kk = 0; kk < 8; kk++) afrag[kk] = ldb8(aPtr + kk * 32);
  float rAddv[4];
  #pragma unroll
  for (int r = 0; r < 4; r++) rAddv[r] = rowAdd[((size_t)b << 10) + c0 + quad * 4 + r];

  float rowSum[4] = {0.f, 0.f, 0.f, 0.f};
  for (int qt = 0; qt < 32; qt++) {
    int q0 = qt * 16;
    const unsigned short* bPtr = Qb + (((size_t)b << 9) + q0 + col) * DDim + quad * 8;
    f32x4 acc = {0.f, 0.f, 0.f, 0.f};
    #pragma unroll
    for (int kk = 0; kk < 8; kk++) acc = MFMA16(afrag[kk], ldb8(bPtr + kk * 32), acc);
    float cAdd = colAdd[((size_t)b << 9) + q0 + col];
    float csum = 0.f;
    #pragma unroll
    for (int r = 0; r < 4; r++) {
      float e = __expf(acc[r] + rAddv[r] + cAdd);
      rowSum[r] += e;
      csum += e;
    }
    csum += __shfl_xor(csum, 16);
    csum += __shfl_xor(csum, 32);
    if (lane < 16) atomicAdd(&colAcc[q0 + lane], csum);
  }
  #pragma unroll
  for (int r = 0; r < 4; r++) {
    float s = rowSum[r];
    s += __shfl_xor(s, 1); s += __shfl_xor(s, 2);
    s += __shfl_xor(s, 4); s += __shfl_xor(s, 8);
    if (col == 0) rowL[((size_t)b << 10) + c0 + quad * 4 + r] = s;
  }
  __syncthreads();
  for (int i = t; i < LQq; i += 256) atomicAdd(&colL[((size_t)b << 9) + i], colAcc[i]);
}

// ---------------------------------------------------------------------------
// k_T: TT[b][d][q] = bf16( sum_c P2[c][q] * C[c][d] ),  P2 = exp(S)/colL[q]
// grid: B*8 blocks (b, q-tile of 64), 4 waves; wave w -> q-band of 16
// ---------------------------------------------------------------------------
__global__ __launch_bounds__(256, 2) void k_T(const unsigned short* __restrict__ Cw,
    const unsigned short* __restrict__ Qb, const unsigned short* __restrict__ CT,
    const float* __restrict__ rowAdd, const float* __restrict__ colAdd,
    const float* __restrict__ colL, unsigned short* __restrict__ TT) {
  int blk = blockIdx.x;
  int b = blk >> 3, qt = blk & 7;
  int t = threadIdx.x, w = t >> 6, lane = t & 63;
  int col = lane & 15, quad = lane >> 4;
  int q0 = qt * 64 + w * 16;
  __shared__ unsigned short pT[4][16 * 40];   // per-wave P2^T tile: 16 q-rows x 32 c (pad->40)
  __shared__ float rAddS[LCc];
  for (int i = t; i < LCc; i += 256) rAddS[i] = rowAdd[((size_t)b << 10) + i];
  __syncthreads();

  const unsigned short* qPtr = Qb + (((size_t)b << 9) + q0 + col) * DDim + quad * 8;
  bf16x8 qfrag[8];
  #pragma unroll
  for (int kk = 0; kk < 8; kk++) qfrag[kk] = ldb8(qPtr + kk * 32);
  float cAdd = colAdd[((size_t)b << 9) + q0 + col];
  float cInv = 1.0f / colL[((size_t)b << 9) + q0 + col];

  f32x4 accT[16];
  #pragma unroll
  for (int nt = 0; nt < 16; nt++) accT[nt] = (f32x4){0.f, 0.f, 0.f, 0.f};

  unsigned short* myT = pT[w];
  for (int cs = 0; cs < 32; cs++) {
    int c0 = cs * 32;
    #pragma unroll
    for (int mt = 0; mt < 2; mt++) {
      const unsigned short* aPtr = Cw + (((size_t)b << 10) + c0 + mt * 16 + col) * DDim + quad * 8;
      f32x4 s = {0.f, 0.f, 0.f, 0.f};
      #pragma unroll
      for (int kk = 0; kk < 8; kk++) s = MFMA16(ldb8(aPtr + kk * 32), qfrag[kk], s);
      // lane holds S at (c_local = mt*16 + quad*4 + r, q_local = col)
      us4 pk;
      #pragma unroll
      for (int r = 0; r < 4; r++) {
        float e = __expf(s[r] + rAddS[c0 + mt * 16 + quad * 4 + r] + cAdd) * cInv;
        pk[r] = f2b(e);
      }
      *(us4*)&myT[col * 40 + mt * 16 + quad * 4] = pk;   // row=q(col), cols=c
    }
    __syncthreads();
    bf16x8 pf = ldb8(&myT[col * 40 + quad * 8]);   // A-frag: m=q(lane&15), k=c(quad*8+j)
    #pragma unroll
    for (int nt = 0; nt < 16; nt++) {
      const unsigned short* cPtr = CT + (((size_t)b << 8) + nt * 16 + col) * LCc + c0 + quad * 8;
      accT[nt] = MFMA16(pf, ldb8(cPtr), accT[nt]);
    }
    __syncthreads();
  }
  // D-layout: col = d_local, quad*4+r = q_local -> store transposed TT (b,d,q)
  #pragma unroll
  for (int nt = 0; nt < 16; nt++) {
    us4 ov;
    #pragma unroll
    for (int r = 0; r < 4; r++) ov[r] = f2b(accT[nt][r]);
    *(us4*)(TT + (((size_t)b << 8) + nt * 16 + col) * LQq + q0 + quad * 4) = ov;
  }
}

// ---------------------------------------------------------------------------
// k_AB: per (b, c-tile of 64): A = P1@Q, BC = P1@T (P1 = exp(S)/rowL), then
// fused epilogue writes out[b][f][c] chunks (C, A, C*A, C*BC) transposed.
// grid: B*16 blocks, 4 waves; wave w -> c-band of 16
// ---------------------------------------------------------------------------
__global__ __launch_bounds__(256, 2) void k_AB(const unsigned short* __restrict__ Cw,
    const unsigned short* __restrict__ Qb, const unsigned short* __restrict__ QT,
    const unsigned short* __restrict__ TT, const float* __restrict__ rowAdd,
    const float* __restrict__ colAdd, const float* __restrict__ rowL,
    const float* __restrict__ C, float* __restrict__ out) {
  int blk = blockIdx.x;
  int b = blk >> 4, ct = blk & 15;
  int t = threadIdx.x, w = t >> 6, lane = t & 63;
  int col = lane & 15, quad = lane >> 4;
  int c0 = ct * 64 + w * 16;
  __shared__ unsigned short p1[4][16 * 40];   // per-wave P1 tile: 16 c-rows x 32 q (pad->40)

  const unsigned short* aPtr = Cw + (((size_t)b << 10) + c0 + col) * DDim + quad * 8;
  bf16x8 afrag[8];
  #pragma unroll
  for (int kk = 0; kk < 8; kk++) afrag[kk] = ldb8(aPtr + kk * 32);
  float rAddv[4], rInv[4];
  #pragma unroll
  for (int r = 0; r < 4; r++) {
    int c = c0 + quad * 4 + r;
    rAddv[r] = rowAdd[((size_t)b << 10) + c];
    rInv[r] = 1.0f / rowL[((size_t)b << 10) + c];
  }

  f32x4 accA[16], accB[16];
  #pragma unroll
  for (int nt = 0; nt < 16; nt++) {
    accA[nt] = (f32x4){0.f, 0.f, 0.f, 0.f};
    accB[nt] = (f32x4){0.f, 0.f, 0.f, 0.f};
  }

  for (int qs = 0; qs < 16; qs++) {
    int q0 = qs * 32;
    #pragma unroll
    for (int ntq = 0; ntq < 2; ntq++) {
      const unsigned short* bPtr = Qb + (((size_t)b << 9) + q0 + ntq * 16 + col) * DDim + quad * 8;
      f32x4 s = {0.f, 0.f, 0.f, 0.f};
      #pragma unroll
      for (int kk = 0; kk < 8; kk++) s = MFMA16(afrag[kk], ldb8(bPtr + kk * 32), s);
      float cAdd = colAdd[((size_t)b << 9) + q0 + ntq * 16 + col];
      #pragma unroll
      for (int r = 0; r < 4; r++) {
        float e = __expf(s[r] + rAddv[r] + cAdd) * rInv[r];
        p1[w][(quad * 4 + r) * 40 + ntq * 16 + col] = f2b(e);
      }
    }
    __syncthreads();
    bf16x8 pf = ldb8(&p1[w][col * 40 + quad * 8]);   // A-frag: m=c, k=q
    int qoff = q0 + quad * 8;
    #pragma unroll
    for (int nt = 0; nt < 16; nt++) {
      size_t rowD = ((size_t)b << 8) + nt * 16 + col;
      accA[nt] = MFMA16(pf, ldb8(QT + rowD * LQq + qoff), accA[nt]);
      accB[nt] = MFMA16(pf, ldb8(TT + rowD * LQq + qoff), accB[nt]);
    }
    __syncthreads();
  }

  // epilogue: out[b][f][cc], f-chunks {d, D+d, 2D+d, 3D+d}, c contiguous
  size_t outB = (size_t)b << 20;   // b * 4D * LC
  int ccBase = c0 + quad * 4;
  #pragma unroll
  for (int nt = 0; nt < 16; nt++) {
    int d = nt * 16 + col;
    float4 vC, vA, vCA, vCB;
    #pragma unroll
    for (int r = 0; r < 4; r++) {
      float Cv = C[((size_t)(ccBase + r) * BB + b) * DDim + d];
      float Av = accA[nt][r];
      ((float*)&vC)[r] = Cv;
      ((float*)&vA)[r] = Av;
      ((float*)&vCA)[r] = Cv * Av;
      ((float*)&vCB)[r] = Cv * accB[nt][r];
    }
    float* o0 = out + outB + (size_t)d * LCc + ccBase;
    *(float4*)(o0) = vC;
    *(float4*)(o0 + DDim * LCc) = vA;
    *(float4*)(o0 + 2 * (size_t)DDim * LCc) = vCA;
    *(float4*)(o0 + 3 * (size_t)DDim * LCc) = vCB;
  }
}

// ---------------------------------------------------------------------------
extern "C" void kernel_launch(void* const* d_in, const int* in_sizes, int n_in,
                              void* d_out, int out_size, void* d_ws, size_t ws_size,
                              hipStream_t stream) {
  const float* C    = (const float*)d_in[0];
  const float* Q    = (const float*)d_in[1];
  const float* w4C  = (const float*)d_in[2];
  const float* w4Q  = (const float*)d_in[3];
  const float* w4mlu= (const float*)d_in[4];
  const float* bias = (const float*)d_in[5];
  float* out = (float*)d_out;
  char* ws = (char*)d_ws;

  // workspace layout (~113 MiB total)
  unsigned short* Cw = (unsigned short*)(ws);                     // 33554432 B
  unsigned short* CT = (unsigned short*)(ws + 33554432);          // 33554432 B
  unsigned short* Qb = (unsigned short*)(ws + 67108864);          // 16777216 B
  unsigned short* QT = (unsigned short*)(ws + 83886080);          // 16777216 B
  unsigned short* TT = (unsigned short*)(ws + 100663296);         // 16777216 B
  float* rowAdd = (float*)(ws + 117440512);                       //   262144 B
  float* colAdd = (float*)(ws + 117702656);                       //   131072 B
  float* rowL   = (float*)(ws + 117833728);                       //   262144 B
  float* colL   = (float*)(ws + 118095872);                       //   131072 B

  prep_C<<<BB * LCc, 256, 0, stream>>>(C, w4C, w4mlu, Cw, rowAdd);
  prep_Q<<<BB * LQq, 256, 0, stream>>>(Q, w4Q, bias, Qb, colAdd, colL);
  transpose_b16<<<dim3(LCc / 64, DDim / 64, BB), 256, 0, stream>>>(C, CT, LCc);
  transpose_b16<<<dim3(LQq / 64, DDim / 64, BB), 256, 0, stream>>>(Q, QT, LQq);
  k_stats<<<BB * 16, 256, 0, stream>>>(Cw, Qb, rowAdd, colAdd, rowL, colL);
  k_T<<<BB * 8, 256, 0, stream>>>(Cw, Qb, CT, rowAdd, colAdd, colL, TT);
  k_AB<<<BB * 16, 256, 0, stream>>>(Cw, Qb, QT, TT, rowAdd, colAdd, rowL, C, out);
}

// Round 2
// 688.549 us; speedup vs baseline: 1.8917x; 1.8917x over previous
//
#include <hip/hip_runtime.h>

#define LCc 1024
#define LQq 512
#define BB  64
#define DDim 256

typedef __attribute__((ext_vector_type(8))) short bf16x8;
typedef __attribute__((ext_vector_type(4))) float f32x4;
typedef __attribute__((ext_vector_type(4))) unsigned short us4;
typedef __attribute__((ext_vector_type(8))) unsigned short us8;

static __device__ __forceinline__ unsigned short f2b(float f) {
  unsigned u = __builtin_bit_cast(unsigned, f);
  unsigned r = u + 0x7FFFu + ((u >> 16) & 1u);   // RNE to bf16
  return (unsigned short)(r >> 16);
}
static __device__ __forceinline__ bf16x8 ldb8(const unsigned short* p) {
  return *(const bf16x8*)p;
}
static __device__ __forceinline__ f32x4 MFMA16(bf16x8 a, bf16x8 b, f32x4 c) {
  return __builtin_amdgcn_mfma_f32_16x16x32_bf16(a, b, c, 0, 0, 0);
}
// async global->LDS, 16B per lane; LDS dest = base + lane*16 (HW-scattered)
static __device__ __forceinline__ void gload16(const unsigned short* g, unsigned short* l) {
  __builtin_amdgcn_global_load_lds(
      (const __attribute__((address_space(1))) unsigned int*)g,
      (__attribute__((address_space(3))) unsigned int*)l, 16, 0, 0);
}

// ---------------------------------------------------------------------------
// prep_CF: read C once -> Cw=bf16(C*w4mlu) (b,c,d); CT=bf16(C) (b,d,c);
//          rowAdd[b][c]=dot(C_row,w4C). grid (LC/64, B), 256 thr.
// ---------------------------------------------------------------------------
__global__ __launch_bounds__(256, 4) void prep_CF(const float* __restrict__ C,
    const float* __restrict__ w4C, const float* __restrict__ w4mlu,
    unsigned short* __restrict__ Cw, unsigned short* __restrict__ CT,
    float* __restrict__ rowAdd) {
  __shared__ unsigned short tile[64][65];
  int c0 = blockIdx.x * 64, b = blockIdx.y;
  int t = threadIdx.x, r = t >> 2, g = t & 3;
  float rsum = 0.f;
  for (int dch = 0; dch < 4; dch++) {
    int d0 = dch * 64;
    const float* src = C + ((size_t)(c0 + r) * BB + b) * DDim + d0 + g * 16;
    unsigned short cwv[16];
    #pragma unroll
    for (int i = 0; i < 4; i++) {
      float4 v = ((const float4*)src)[i];
      float4 wm = *(const float4*)(w4mlu + d0 + g * 16 + i * 4);
      float4 wc = *(const float4*)(w4C + d0 + g * 16 + i * 4);
      rsum += v.x * wc.x + v.y * wc.y + v.z * wc.z + v.w * wc.w;
      cwv[i * 4 + 0] = f2b(v.x * wm.x);
      cwv[i * 4 + 1] = f2b(v.y * wm.y);
      cwv[i * 4 + 2] = f2b(v.z * wm.z);
      cwv[i * 4 + 3] = f2b(v.w * wm.w);
      tile[r][g * 16 + i * 4 + 0] = f2b(v.x);
      tile[r][g * 16 + i * 4 + 1] = f2b(v.y);
      tile[r][g * 16 + i * 4 + 2] = f2b(v.z);
      tile[r][g * 16 + i * 4 + 3] = f2b(v.w);
    }
    unsigned short* cwp = Cw + ((size_t)((b << 10) + c0 + r)) * DDim + d0 + g * 16;
    *(us8*)cwp = *(us8*)&cwv[0];
    *(us8*)(cwp + 8) = *(us8*)&cwv[8];
    __syncthreads();
    // CT rows d0+r, cols c0+g*16..+15
    unsigned short* ctp = CT + ((size_t)((b << 8) + d0 + r)) * LCc + c0 + g * 16;
    us8 o0, o1;
    #pragma unroll
    for (int j = 0; j < 8; j++) { o0[j] = tile[g * 16 + j][r]; o1[j] = tile[g * 16 + 8 + j][r]; }
    *(us8*)ctp = o0;
    *(us8*)(ctp + 8) = o1;
    __syncthreads();
  }
  rsum += __shfl_xor(rsum, 1);
  rsum += __shfl_xor(rsum, 2);
  if (g == 0) rowAdd[((size_t)b << 10) + c0 + r] = rsum;
}

// ---------------------------------------------------------------------------
// prep_QF: read Q once -> Qb=bf16(Q) (b,q,d); QT=bf16(Q) (b,d,q);
//          colAdd=dot(Q_row,w4Q)+bias; colL=0. grid (LQ/64, B).
// ---------------------------------------------------------------------------
__global__ __launch_bounds__(256, 4) void prep_QF(const float* __restrict__ Q,
    const float* __restrict__ w4Q, const float* __restrict__ bias,
    unsigned short* __restrict__ Qb, unsigned short* __restrict__ QT,
    float* __restrict__ colAdd, float* __restrict__ colL) {
  __shared__ unsigned short tile[64][65];
  int q0 = blockIdx.x * 64, b = blockIdx.y;
  int t = threadIdx.x, r = t >> 2, g = t & 3;
  float rsum = 0.f;
  for (int dch = 0; dch < 4; dch++) {
    int d0 = dch * 64;
    const float* src = Q + ((size_t)(q0 + r) * BB + b) * DDim + d0 + g * 16;
    #pragma unroll
    for (int i = 0; i < 4; i++) {
      float4 v = ((const float4*)src)[i];
      float4 wq = *(const float4*)(w4Q + d0 + g * 16 + i * 4);
      rsum += v.x * wq.x + v.y * wq.y + v.z * wq.z + v.w * wq.w;
      tile[r][g * 16 + i * 4 + 0] = f2b(v.x);
      tile[r][g * 16 + i * 4 + 1] = f2b(v.y);
      tile[r][g * 16 + i * 4 + 2] = f2b(v.z);
      tile[r][g * 16 + i * 4 + 3] = f2b(v.w);
    }
    __syncthreads();
    unsigned short* qbp = Qb + ((size_t)((b << 9) + q0 + r)) * DDim + d0 + g * 16;
    us8 s0, s1;
    #pragma unroll
    for (int j = 0; j < 8; j++) { s0[j] = tile[r][g * 16 + j]; s1[j] = tile[r][g * 16 + 8 + j]; }
    *(us8*)qbp = s0;
    *(us8*)(qbp + 8) = s1;
    unsigned short* qtp = QT + ((size_t)((b << 8) + d0 + r)) * LQq + q0 + g * 16;
    us8 o0, o1;
    #pragma unroll
    for (int j = 0; j < 8; j++) { o0[j] = tile[g * 16 + j][r]; o1[j] = tile[g * 16 + 8 + j][r]; }
    *(us8*)qtp = o0;
    *(us8*)(qtp + 8) = o1;
    __syncthreads();
  }
  rsum += __shfl_xor(rsum, 1);
  rsum += __shfl_xor(rsum, 2);
  if (g == 0) {
    colAdd[((size_t)b << 9) + q0 + r] = rsum + bias[0];
    colL[((size_t)b << 9) + q0 + r] = 0.0f;
  }
}

// ---------------------------------------------------------------------------
// k_P: E = exp(Cw@Qb^T + rowAdd + colAdd) stored as fragment-ready tiles
//      Ptiles[((b*64+cb)*16+qs)*512 + lane*8]; rowL direct; colL atomic.
// grid B*16 (b, c-tile 64), 4 waves, wave w -> c-band w.
// ---------------------------------------------------------------------------
__global__ __launch_bounds__(256, 3) void k_P(const unsigned short* __restrict__ Cw,
    const unsigned short* __restrict__ Qb, const float* __restrict__ rowAdd,
    const float* __restrict__ colAdd, unsigned short* __restrict__ Pt,
    float* __restrict__ rowL, float* __restrict__ colL) {
  int blk = blockIdx.x;
  int b = blk >> 4, ct = blk & 15;
  int t = threadIdx.x, w = t >> 6, lane = t & 63;
  int col = lane & 15, quad = lane >> 4;
  int c0w = ct * 64 + w * 16;
  __shared__ unsigned short tile[2][64][40];   // [buf][c-local 64][q-window 32 pad 40]
  __shared__ float colAcc[LQq];
  for (int i = t; i < LQq; i += 256) colAcc[i] = 0.f;
  __syncthreads();

  bf16x8 afrag[8];
  const unsigned short* aPtr = Cw + ((size_t)((b << 10) + c0w + col)) * DDim + quad * 8;
  #pragma unroll
  for (int kk = 0; kk < 8; kk++) afrag[kk] = ldb8(aPtr + kk * 32);
  float rAddv[4];
  #pragma unroll
  for (int r = 0; r < 4; r++) rAddv[r] = rowAdd[((size_t)b << 10) + c0w + quad * 4 + r];
  float rowSum[4] = {0.f, 0.f, 0.f, 0.f};

  int cur = 0;
  for (int win = 0; win < 16; win++) {
    #pragma unroll
    for (int h = 0; h < 2; h++) {
      int q0 = win * 32 + h * 16;
      const unsigned short* bPtr = Qb + ((size_t)((b << 9) + q0 + col)) * DDim + quad * 8;
      f32x4 acc = {0.f, 0.f, 0.f, 0.f};
      #pragma unroll
      for (int kk = 0; kk < 8; kk++) acc = MFMA16(afrag[kk], ldb8(bPtr + kk * 32), acc);
      float cAdd = colAdd[((size_t)b << 9) + q0 + col];
      float csum = 0.f;
      #pragma unroll
      for (int r = 0; r < 4; r++) {
        float e = __expf(acc[r] + rAddv[r] + cAdd);
        rowSum[r] += e;
        csum += e;
        tile[cur][w * 16 + quad * 4 + r][h * 16 + col] = f2b(e);
      }
      csum += __shfl_xor(csum, 16);
      csum += __shfl_xor(csum, 32);
      if (lane < 16) atomicAdd(&colAcc[q0 + lane], csum);
    }
    __syncthreads();
    // assemble + store this window's P tile for band w (1 KB, coalesced)
    us8 frag = *(const us8*)&tile[cur][w * 16 + col][quad * 8];
    *(us8*)(Pt + (((size_t)(b * 64 + ct * 4 + w) * 16 + win) << 9) + lane * 8) = frag;
    cur ^= 1;
  }
  #pragma unroll
  for (int r = 0; r < 4; r++) {
    float s = rowSum[r];
    s += __shfl_xor(s, 1); s += __shfl_xor(s, 2);
    s += __shfl_xor(s, 4); s += __shfl_xor(s, 8);
    if (col == 0) rowL[((size_t)b << 10) + c0w + quad * 4 + r] = s;
  }
  __syncthreads();
  for (int i = t; i < LQq; i += 256) atomicAdd(&colL[((size_t)b << 9) + i], colAcc[i]);
}

// ---------------------------------------------------------------------------
// k_T: TT[b][d][q] = bf16( sum_c E[c][q]/colL[q] * C[c][d] )
// grid B*16 (b, qs = q-window 32), 4 waves; wave w -> d-quarter w*64.
// A-frags via tiny cooperative LDS transpose of P tiles; B = CT streaming.
// ---------------------------------------------------------------------------
__global__ __launch_bounds__(256, 4) void k_T(const unsigned short* __restrict__ Pt,
    const unsigned short* __restrict__ CT, const float* __restrict__ colL,
    unsigned short* __restrict__ TT) {
  int blk = blockIdx.x;
  int b = blk >> 4, qs = blk & 15;
  int t = threadIdx.x, w = t >> 6, lane = t & 63;
  int col = lane & 15, quad = lane >> 4;
  int dq = w * 64;
  int cbl = w & 1, jh = w >> 1;     // this wave's transform share
  __shared__ unsigned short pT[32][40];   // [q-local 32][c-chunk 32 pad 40]

  f32x4 accT[2][4];
  #pragma unroll
  for (int mf = 0; mf < 2; mf++)
    #pragma unroll
    for (int nf = 0; nf < 4; nf++) accT[mf][nf] = (f32x4){0.f, 0.f, 0.f, 0.f};

  us8 frag = *(const us8*)(Pt + (((size_t)(b * 64 + 0 * 2 + cbl) * 16 + qs) << 9) + lane * 8);
  for (int cs = 0; cs < 32; cs++) {
    bf16x8 bf[4];
    #pragma unroll
    for (int nf = 0; nf < 4; nf++)
      bf[nf] = ldb8(CT + ((size_t)((b << 8) + dq + nf * 16 + col)) * LCc + cs * 32 + quad * 8);
    // write this wave's quarter of the 32x32 transpose chunk
    #pragma unroll
    for (int jj = 0; jj < 4; jj++) {
      int j = jh * 4 + jj;
      pT[quad * 8 + j][cbl * 16 + col] = (unsigned short)frag[j];
    }
    __syncthreads();
    bf16x8 pa[2];
    #pragma unroll
    for (int mf = 0; mf < 2; mf++) pa[mf] = *(const bf16x8*)&pT[mf * 16 + col][quad * 8];
    #pragma unroll
    for (int mf = 0; mf < 2; mf++)
      #pragma unroll
      for (int nf = 0; nf < 4; nf++) accT[mf][nf] = MFMA16(pa[mf], bf[nf], accT[mf][nf]);
    if (cs < 31)
      frag = *(const us8*)(Pt + (((size_t)(b * 64 + (cs + 1) * 2 + cbl) * 16 + qs) << 9) + lane * 8);
    __syncthreads();
  }
  float cInv[2][4];
  #pragma unroll
  for (int mf = 0; mf < 2; mf++)
    #pragma unroll
    for (int r = 0; r < 4; r++)
      cInv[mf][r] = 1.0f / colL[((size_t)b << 9) + qs * 32 + mf * 16 + quad * 4 + r];
  #pragma unroll
  for (int mf = 0; mf < 2; mf++)
    #pragma unroll
    for (int nf = 0; nf < 4; nf++) {
      us4 ov;
      #pragma unroll
      for (int r = 0; r < 4; r++) ov[r] = f2b(accT[mf][nf][r] * cInv[mf][r]);
      *(us4*)(TT + ((size_t)((b << 8) + dq + nf * 16 + col)) * LQq + qs * 32 + mf * 16 + quad * 4) = ov;
    }
}

// ---------------------------------------------------------------------------
// k_AB: A = (E/rowL)@Q, B = (E/rowL)@T; fused epilogue -> out (B,4D,LC).
// grid B*16 (b, c-tile 64), 4 waves; wave w -> d-quarter w*64.
// A-frags direct from Ptiles; QT/TT staged via global_load_lds double-buffer.
// ---------------------------------------------------------------------------
__global__ __launch_bounds__(256, 2) void k_AB(const unsigned short* __restrict__ Pt,
    const unsigned short* __restrict__ QT, const unsigned short* __restrict__ TT,
    const float* __restrict__ rowL, const float* __restrict__ C,
    float* __restrict__ out) {
  int blk = blockIdx.x;
  int b = blk >> 4, ct = blk & 15;
  int t = threadIdx.x, w = t >> 6, lane = t & 63;
  int col = lane & 15, quad = lane >> 4;
  int dq = w * 64;
  __shared__ unsigned short sb[4][2][8][512];   // 64 KiB: wave x dbuf x 8 slabs x 1KB

  f32x4 accA[4][4], accB[4][4];
  #pragma unroll
  for (int mf = 0; mf < 4; mf++)
    #pragma unroll
    for (int nf = 0; nf < 4; nf++) {
      accA[mf][nf] = (f32x4){0.f, 0.f, 0.f, 0.f};
      accB[mf][nf] = (f32x4){0.f, 0.f, 0.f, 0.f};
    }

  // stage(qs, buf): 8 async wave-loads, lane->16B identity layout
  #define STAGE(qs_, buf_)                                                              \
    {                                                                                   \
      int _q = (qs_) * 32 + quad * 8;                                                   \
      _Pragma("unroll")                                                                 \
      for (int nf = 0; nf < 4; nf++) {                                                  \
        size_t rowD = (size_t)((b << 8) + dq + nf * 16 + col);                          \
        gload16(QT + (rowD << 9) + _q, &sb[w][buf_][nf][0]);                            \
        gload16(TT + (rowD << 9) + _q, &sb[w][buf_][4 + nf][0]);                        \
      }                                                                                 \
    }

  bf16x8 pa[4], paN[4];
  #pragma unroll
  for (int mf = 0; mf < 4; mf++)
    pa[mf] = ldb8(Pt + (((size_t)(b * 64 + ct * 4 + mf) * 16 + 0) << 9) + lane * 8);
  STAGE(0, 0);
  __syncthreads();

  for (int qs = 0; qs < 16; qs++) {
    int bufr = qs & 1;
    if (qs < 15) {
      STAGE(qs + 1, bufr ^ 1);
      #pragma unroll
      for (int mf = 0; mf < 4; mf++)
        paN[mf] = ldb8(Pt + (((size_t)(b * 64 + ct * 4 + mf) * 16 + qs + 1) << 9) + lane * 8);
    }
    bf16x8 bq[4], bt[4];
    #pragma unroll
    for (int nf = 0; nf < 4; nf++) {
      bq[nf] = ldb8(&sb[w][bufr][nf][lane * 8]);
      bt[nf] = ldb8(&sb[w][bufr][4 + nf][lane * 8]);
    }
    #pragma unroll
    for (int mf = 0; mf < 4; mf++)
      #pragma unroll
      for (int nf = 0; nf < 4; nf++) {
        accA[mf][nf] = MFMA16(pa[mf], bq[nf], accA[mf][nf]);
        accB[mf][nf] = MFMA16(pa[mf], bt[nf], accB[mf][nf]);
      }
    if (qs < 15) {
      #pragma unroll
      for (int mf = 0; mf < 4; mf++) pa[mf] = paN[mf];
    }
    __syncthreads();
  }

  // epilogue: scale by 1/rowL, multiply with C, write 4 chunks transposed
  float rInv[4][4];
  #pragma unroll
  for (int mf = 0; mf < 4; mf++) {
    float4 rv = *(const float4*)(rowL + ((size_t)b << 10) + ct * 64 + mf * 16 + quad * 4);
    rInv[mf][0] = 1.0f / rv.x; rInv[mf][1] = 1.0f / rv.y;
    rInv[mf][2] = 1.0f / rv.z; rInv[mf][3] = 1.0f / rv.w;
  }
  size_t outB = (size_t)b << 20;
  #pragma unroll
  for (int mf = 0; mf < 4; mf++) {
    int cc = ct * 64 + mf * 16 + quad * 4;
    #pragma unroll
    for (int nf = 0; nf < 4; nf++) {
      int d = dq + nf * 16 + col;
      float4 vC, vA, vCA, vCB;
      #pragma unroll
      for (int r = 0; r < 4; r++) {
        float Cv = C[((size_t)(cc + r) * BB + b) * DDim + d];
        float Av = accA[mf][nf][r] * rInv[mf][r];
        float Bv = accB[mf][nf][r] * rInv[mf][r];
        ((float*)&vC)[r] = Cv;
        ((float*)&vA)[r] = Av;
        ((float*)&vCA)[r] = Cv * Av;
        ((float*)&vCB)[r] = Cv * Bv;
      }
      float* o0 = out + outB + (size_t)d * LCc + cc;
      *(float4*)(o0) = vC;
      *(float4*)(o0 + (size_t)DDim * LCc) = vA;
      *(float4*)(o0 + 2 * (size_t)DDim * LCc) = vCA;
      *(float4*)(o0 + 3 * (size_t)DDim * LCc) = vCB;
    }
  }
  #undef STAGE
}

// ---------------------------------------------------------------------------
extern "C" void kernel_launch(void* const* d_in, const int* in_sizes, int n_in,
                              void* d_out, int out_size, void* d_ws, size_t ws_size,
                              hipStream_t stream) {
  const float* C    = (const float*)d_in[0];
  const float* Q    = (const float*)d_in[1];
  const float* w4C  = (const float*)d_in[2];
  const float* w4Q  = (const float*)d_in[3];
  const float* w4mlu= (const float*)d_in[4];
  const float* bias = (const float*)d_in[5];
  float* out = (float*)d_out;
  char* ws = (char*)d_ws;

  // workspace layout (~161 MiB; TT aliases Qb — Qb dead after k_P)
  unsigned short* Cw = (unsigned short*)(ws);                       // 33554432
  unsigned short* CT = (unsigned short*)(ws + 33554432);            // 33554432
  unsigned short* Qb = (unsigned short*)(ws + 67108864);            // 16777216
  unsigned short* TT = Qb;                                          // alias
  unsigned short* QT = (unsigned short*)(ws + 83886080);            // 16777216
  unsigned short* Pt = (unsigned short*)(ws + 100663296);           // 67108864
  float* rowAdd = (float*)(ws + 167772160);                         //   262144
  float* colAdd = (float*)(ws + 168034304);                         //   131072
  float* rowL   = (float*)(ws + 168165376);                         //   262144
  float* colL   = (float*)(ws + 168427520);                         //   131072

  prep_CF<<<dim3(LCc / 64, BB), 256, 0, stream>>>(C, w4C, w4mlu, Cw, CT, rowAdd);
  prep_QF<<<dim3(LQq / 64, BB), 256, 0, stream>>>(Q, w4Q, bias, Qb, QT, colAdd, colL);
  k_P<<<BB * 16, 256, 0, stream>>>(Cw, Qb, rowAdd, colAdd, Pt, rowL, colL);
  k_T<<<BB * 16, 256, 0, stream>>>(Pt, CT, colL, TT);
  k_AB<<<BB * 16, 256, 0, stream>>>(Pt, QT, TT, rowL, C, out);
}